// Round 1
// baseline (439.765 us; speedup 1.0000x reference)
//
#include <hip/hip_runtime.h>
#include <hip/hip_bf16.h>
#include <cstdint>
#include <cstddef>

// ---------------------------------------------------------------------------
// RelativePositionMultiHeadAttention  (B=32,G=64,P=64,D=384,H=12,DH=32)
// Plan: prep (weightT->bf16, scale-folded K, dense bias) ->
//       fused per-(b,g) QKV-GEMM + attention (bf16 MFMA 16x16x32) ->
//       merge GEMM.
// ---------------------------------------------------------------------------

typedef __bf16 bf16_t;
typedef __bf16 bf16x8 __attribute__((ext_vector_type(8)));
typedef float  f32x4  __attribute__((ext_vector_type(4)));

#define MFMA16(A, B, C) __builtin_amdgcn_mfma_f32_16x16x32_bf16((A), (B), (C), 0, 0, 0)

#define NBLK   2048          // B*G
#define SCALE  0.051031036307982884f  // 384^-0.5

// LDS geometry for fused kernel (element = bf16). Strides chosen so that
// ds_read_b128 fragment reads are 16B-aligned and <=2-way bank conflicted.
#define XS   408             // x row stride   (word-stride 204 -> bank 12c: 2-way)
#define QKS  40              // q/k row stride (word-stride 20  -> bank 20c: 2-way)
#define VTS  88              // vT / P row stride (word-stride 44 -> bank 12c: 2-way)
#define OFF_X 0
#define OFF_Q (64 * XS)                  // 26112
#define OFF_K (OFF_Q + 4 * 64 * QKS)     // 36352
#define OFF_V (OFF_K + 4 * 64 * QKS)     // 46592
#define OFF_P (OFF_V + 4 * 32 * VTS)     // 57856
#define LDS_ELEMS (OFF_P + 8 * 32 * VTS) // 80384
#define LDS_BYTES (LDS_ELEMS * 2)        // 160768  (<= 163840)

// ---------------------------------------------------------------------------
// prep: qkv_wT (bf16, scale folded into K rows), merge_wT (bf16),
//       dense bias [12][64][64] f32, scaled qkv bias f32.
// ---------------------------------------------------------------------------
__global__ void prep_kernel(const float* __restrict__ qkv_w,
                            const float* __restrict__ qkv_b,
                            const float* __restrict__ merge_w,
                            const float* __restrict__ bias_table,
                            const int*   __restrict__ rel_index,
                            bf16_t* __restrict__ qkv_wT,
                            bf16_t* __restrict__ merge_wT,
                            float*  __restrict__ biasx,
                            float*  __restrict__ qkvb_s) {
  int idx = blockIdx.x * 256 + threadIdx.x;
  if (idx < 1152 * 384) {               // qkv_wT[n][k] = qkv_w[k][n] (*scale for K)
    int n = idx / 384, k = idx - n * 384;
    float v = qkv_w[k * 1152 + n];
    if (n >= 384 && n < 768) v *= SCALE;
    qkv_wT[idx] = (bf16_t)v;
    return;
  }
  int i2 = idx - 1152 * 384;
  if (i2 < 384 * 384) {                 // merge_wT[n][k] = merge_w[k][n]
    int n = i2 / 384, k = i2 - n * 384;
    merge_wT[i2] = (bf16_t)merge_w[k * 384 + n];
    return;
  }
  int i3 = i2 - 384 * 384;
  if (i3 < 12 * 64 * 64) {              // biasx[h][i*64+j]
    int h = i3 / 4096, r = i3 - h * 4096;
    biasx[i3] = bias_table[rel_index[r] * 12 + h];
    return;
  }
  int i4 = i3 - 12 * 64 * 64;
  if (i4 < 1152) {
    float v = qkv_b[i4];
    if (i4 >= 384 && i4 < 768) v *= SCALE;
    qkvb_s[i4] = v;
  }
}

// ---------------------------------------------------------------------------
// fused QKV + attention. One block per (b,g). 8 waves.
// 3 passes x 4 heads: QKV GEMM (M=64,N=384,K=384 per pass) -> LDS,
// then per-wave item = (head, i-half):  S^T = K*Q^T  (j rows, i cols),
// softmax over j via 2x shfl_xor, P->LDS scratch, O^T = V^T * P^T.
// ---------------------------------------------------------------------------
__global__ void __launch_bounds__(512)
fused_qkv_attn(const float*  __restrict__ x,
               const bf16_t* __restrict__ wT,
               const float*  __restrict__ qbias,
               const float*  __restrict__ biasx,
               bf16_t* __restrict__ attn) {
  extern __shared__ char smem_raw[];
  bf16_t* lds = (bf16_t*)smem_raw;
  bf16_t* xs  = lds + OFF_X;   // [64][XS]
  bf16_t* qs  = lds + OFF_Q;   // [4][64][QKS]  q[hl][token][d]
  bf16_t* ks  = lds + OFF_K;   // [4][64][QKS]  k[hl][token][d] (scale folded)
  bf16_t* vts = lds + OFF_V;   // [4][32][VTS]  vT[hl][d][token]
  bf16_t* ps  = lds + OFF_P;   // [8][32][VTS]  per-wave P[i_local][j]

  const int tid  = threadIdx.x;
  const int blk  = blockIdx.x;
  const int lane = tid & 63;
  const int w    = tid >> 6;   // wave 0..7
  const int c    = lane & 15;
  const int g    = lane >> 4;

  const f32x4 zf = {0.f, 0.f, 0.f, 0.f};

  // ---- stage x -> LDS bf16 (coalesced float4) ----
  {
    const float4* xg = (const float4*)(x + (size_t)blk * (64 * 384));
#pragma unroll
    for (int it = 0; it < 12; ++it) {
      int idx = tid + it * 512;          // 0..6143, 96 float4 per row
      int row = idx / 96;
      int col = (idx - row * 96) * 4;
      float4 v = xg[idx];
      union { bf16_t b[4]; uint2 u; } pk;
      pk.b[0] = (bf16_t)v.x; pk.b[1] = (bf16_t)v.y;
      pk.b[2] = (bf16_t)v.z; pk.b[3] = (bf16_t)v.w;
      *(uint2*)(xs + row * XS + col) = pk.u;
    }
  }
  __syncthreads();

#pragma unroll 1
  for (int pass = 0; pass < 3; ++pass) {
    // ---------------- QKV GEMM: wave owns 3 n-tiles of 16 ----------------
    f32x4 acc[3][4];
#pragma unroll
    for (int t = 0; t < 3; ++t)
#pragma unroll
      for (int mt = 0; mt < 4; ++mt) acc[t][mt] = zf;

    int nrow[3];
    const bf16_t* wp[3];
#pragma unroll
    for (int t = 0; t < 3; ++t) {
      int tau  = w * 3 + t;              // 0..23
      int kind = tau >> 3;               // 0=Q 1=K 2=V
      int u    = tau & 7;
      nrow[t]  = kind * 384 + (pass * 4 + (u >> 1)) * 32 + (u & 1) * 16;
      wp[t]    = wT + (size_t)(nrow[t] + c) * 384 + g * 8;
    }
    bf16x8 bc[3], bn[3];
#pragma unroll
    for (int t = 0; t < 3; ++t) bc[t] = *(const bf16x8*)(wp[t]);
#pragma unroll
    for (int k = 0; k < 12; ++k) {
      if (k < 11) {
#pragma unroll
        for (int t = 0; t < 3; ++t) bn[t] = *(const bf16x8*)(wp[t] + (k + 1) * 32);
      }
      bf16x8 a[4];
#pragma unroll
      for (int mt = 0; mt < 4; ++mt)
        a[mt] = *(const bf16x8*)(xs + (mt * 16 + c) * XS + k * 32 + g * 8);
#pragma unroll
      for (int t = 0; t < 3; ++t)
#pragma unroll
        for (int mt = 0; mt < 4; ++mt)
          acc[t][mt] = MFMA16(a[mt], bc[t], acc[t][mt]);
#pragma unroll
      for (int t = 0; t < 3; ++t) bc[t] = bn[t];
    }

    __syncthreads();   // previous pass's attention reads are done

    // ---------------- epilogue: Q/K/V -> LDS ----------------
#pragma unroll
    for (int t = 0; t < 3; ++t) {
      int tau  = w * 3 + t;
      int kind = tau >> 3;
      int u    = tau & 7;
      int hl   = u >> 1, c16 = u & 1;
      float bv = qbias[nrow[t] + c];
      if (kind == 2) {                   // V stored transposed: [d][token]
#pragma unroll
        for (int mt = 0; mt < 4; ++mt) {
          union { bf16_t b[4]; uint2 u2; } pk;
#pragma unroll
          for (int r = 0; r < 4; ++r) pk.b[r] = (bf16_t)(acc[t][mt][r] + bv);
          *(uint2*)(vts + (hl * 32 + c16 * 16 + c) * VTS + mt * 16 + g * 4) = pk.u2;
        }
      } else {                           // Q/K: [token][d]
        bf16_t* dst = (kind == 0 ? qs : ks) + hl * 64 * QKS + c16 * 16 + c;
#pragma unroll
        for (int mt = 0; mt < 4; ++mt)
#pragma unroll
          for (int r = 0; r < 4; ++r)
            dst[(mt * 16 + g * 4 + r) * QKS] = (bf16_t)(acc[t][mt][r] + bv);
      }
    }
    __syncthreads();

    // ---------------- attention: item = (hl = w>>1, ih = w&1) ----------------
    {
      const int hl = w >> 1, ih = w & 1;
      const int h  = pass * 4 + hl;

      // S^T = K * Q^T : A = K[j][d] frags, B = Q[i][d] frags (same read pattern)
      f32x4 sacc[4][2];
#pragma unroll
      for (int mt = 0; mt < 4; ++mt)
#pragma unroll
        for (int nt = 0; nt < 2; ++nt) sacc[mt][nt] = zf;
      bf16x8 ka[4], qf[2];
#pragma unroll
      for (int mt = 0; mt < 4; ++mt)
        ka[mt] = *(const bf16x8*)(ks + (hl * 64 + mt * 16 + c) * QKS + g * 8);
#pragma unroll
      for (int nt = 0; nt < 2; ++nt)
        qf[nt] = *(const bf16x8*)(qs + (hl * 64 + ih * 32 + nt * 16 + c) * QKS + g * 8);
#pragma unroll
      for (int mt = 0; mt < 4; ++mt)
#pragma unroll
        for (int nt = 0; nt < 2; ++nt)
          sacc[mt][nt] = MFMA16(ka[mt], qf[nt], sacc[mt][nt]);

      // lane holds S^T[j][i]: i = ih*32 + nt*16 + c,  j = mt*16 + g*4 + r
      const float* bp = biasx + h * 4096;
      float sv[4][2][4];
      float mx[2] = {-3.0e38f, -3.0e38f};
#pragma unroll
      for (int nt = 0; nt < 2; ++nt) {
        int i = ih * 32 + nt * 16 + c;
#pragma unroll
        for (int mt = 0; mt < 4; ++mt) {
          union { float4 v; float a[4]; } bb;
          bb.v = *(const float4*)(bp + i * 64 + mt * 16 + g * 4);
#pragma unroll
          for (int r = 0; r < 4; ++r) {
            float s = sacc[mt][nt][r] + bb.a[r];
            sv[mt][nt][r] = s;
            mx[nt] = fmaxf(mx[nt], s);
          }
        }
      }
#pragma unroll
      for (int nt = 0; nt < 2; ++nt) {
        mx[nt] = fmaxf(mx[nt], __shfl_xor(mx[nt], 16));
        mx[nt] = fmaxf(mx[nt], __shfl_xor(mx[nt], 32));
      }
      float l[2] = {0.f, 0.f};
#pragma unroll
      for (int nt = 0; nt < 2; ++nt)
#pragma unroll
        for (int mt = 0; mt < 4; ++mt)
#pragma unroll
          for (int r = 0; r < 4; ++r) {
            float p = exp2f((sv[mt][nt][r] - mx[nt]) * 1.4426950408889634f);
            sv[mt][nt][r] = p;
            l[nt] += p;
          }
#pragma unroll
      for (int nt = 0; nt < 2; ++nt) {
        l[nt] += __shfl_xor(l[nt], 16);
        l[nt] += __shfl_xor(l[nt], 32);
      }

      // P (unnormalized) -> per-wave LDS scratch, laid out P[i_local][j]
#pragma unroll
      for (int nt = 0; nt < 2; ++nt)
#pragma unroll
        for (int mt = 0; mt < 4; ++mt) {
          union { bf16_t b[4]; uint2 u2; } pk;
#pragma unroll
          for (int r = 0; r < 4; ++r) pk.b[r] = (bf16_t)sv[mt][nt][r];
          *(uint2*)(ps + (w * 32 + nt * 16 + c) * VTS + mt * 16 + g * 4) = pk.u2;
        }

      // O^T = V^T * P^T : A = vT frags, B = P[i][j] frags
      f32x4 oacc[2][2];
#pragma unroll
      for (int m2 = 0; m2 < 2; ++m2)
#pragma unroll
        for (int nt = 0; nt < 2; ++nt) oacc[m2][nt] = zf;
#pragma unroll
      for (int kt = 0; kt < 2; ++kt) {
        bf16x8 va[2], pb[2];
#pragma unroll
        for (int m2 = 0; m2 < 2; ++m2)
          va[m2] = *(const bf16x8*)(vts + (hl * 32 + m2 * 16 + c) * VTS + kt * 32 + g * 8);
#pragma unroll
        for (int nt = 0; nt < 2; ++nt)
          pb[nt] = *(const bf16x8*)(ps + (w * 32 + nt * 16 + c) * VTS + kt * 32 + g * 8);
#pragma unroll
        for (int m2 = 0; m2 < 2; ++m2)
#pragma unroll
          for (int nt = 0; nt < 2; ++nt)
            oacc[m2][nt] = MFMA16(va[m2], pb[nt], oacc[m2][nt]);
      }

      // write attn_out[token][h*32 + d] (bf16), normalize by l
#pragma unroll
      for (int nt = 0; nt < 2; ++nt) {
        float inv = 1.0f / l[nt];
        int row = blk * 64 + ih * 32 + nt * 16 + c;
#pragma unroll
        for (int m2 = 0; m2 < 2; ++m2) {
          union { bf16_t b[4]; uint2 u2; } pk;
#pragma unroll
          for (int r = 0; r < 4; ++r) pk.b[r] = (bf16_t)(oacc[m2][nt][r] * inv);
          *(uint2*)(attn + (size_t)row * 384 + h * 32 + m2 * 16 + g * 4) = pk.u2;
        }
      }
    }
  }
}

// ---------------------------------------------------------------------------
// merge GEMM: out[M=131072][384] = attn(bf16) @ merge_wT' + merge_b, fp32 out.
// One block per 64 rows; A staged in LDS; B streamed from L2 with prefetch.
// ---------------------------------------------------------------------------
__global__ void __launch_bounds__(512)
merge_gemm(const bf16_t* __restrict__ attn,
           const bf16_t* __restrict__ mwT,
           const float*  __restrict__ mb,
           float* __restrict__ out) {
  __shared__ bf16_t as[64 * XS];
  const int tid = threadIdx.x, blk = blockIdx.x;
  const int lane = tid & 63, w = tid >> 6, c = lane & 15, g = lane >> 4;

  {
    const int4* ag = (const int4*)(attn + (size_t)blk * (64 * 384));
#pragma unroll
    for (int it = 0; it < 6; ++it) {
      int idx = tid + it * 512;          // 0..3071, 48 int4 per row
      int row = idx / 48;
      int col = (idx - row * 48) * 8;
      *(int4*)(as + row * XS + col) = ag[idx];
    }
  }
  __syncthreads();

  const f32x4 zf = {0.f, 0.f, 0.f, 0.f};
  f32x4 acc[3][4];
#pragma unroll
  for (int t = 0; t < 3; ++t)
#pragma unroll
    for (int mt = 0; mt < 4; ++mt) acc[t][mt] = zf;

  const int n0 = w * 48;
  const bf16_t* wp[3];
#pragma unroll
  for (int t = 0; t < 3; ++t) wp[t] = mwT + (size_t)(n0 + t * 16 + c) * 384 + g * 8;
  bf16x8 bc[3], bn[3];
#pragma unroll
  for (int t = 0; t < 3; ++t) bc[t] = *(const bf16x8*)(wp[t]);
#pragma unroll
  for (int k = 0; k < 12; ++k) {
    if (k < 11) {
#pragma unroll
      for (int t = 0; t < 3; ++t) bn[t] = *(const bf16x8*)(wp[t] + (k + 1) * 32);
    }
    bf16x8 a[4];
#pragma unroll
    for (int mt = 0; mt < 4; ++mt)
      a[mt] = *(const bf16x8*)(as + (mt * 16 + c) * XS + k * 32 + g * 8);
#pragma unroll
    for (int t = 0; t < 3; ++t)
#pragma unroll
      for (int mt = 0; mt < 4; ++mt)
        acc[t][mt] = MFMA16(a[mt], bc[t], acc[t][mt]);
#pragma unroll
    for (int t = 0; t < 3; ++t) bc[t] = bn[t];
  }

#pragma unroll
  for (int t = 0; t < 3; ++t) {
    float bias = mb[n0 + t * 16 + c];
#pragma unroll
    for (int mt = 0; mt < 4; ++mt)
#pragma unroll
      for (int r = 0; r < 4; ++r)
        out[(size_t)(blk * 64 + mt * 16 + g * 4 + r) * 384 + n0 + t * 16 + c] =
            acc[t][mt][r] + bias;
  }
}

// ---------------------------------------------------------------------------
extern "C" void kernel_launch(void* const* d_in, const int* in_sizes, int n_in,
                              void* d_out, int out_size, void* d_ws, size_t ws_size,
                              hipStream_t stream) {
  const float* x          = (const float*)d_in[0];
  const float* qkv_w      = (const float*)d_in[1];
  const float* qkv_b      = (const float*)d_in[2];
  const float* merge_w    = (const float*)d_in[3];
  const float* merge_b    = (const float*)d_in[4];
  const float* bias_table = (const float*)d_in[5];
  const int*   rel_index  = (const int*)d_in[6];
  float*       out        = (float*)d_out;

  // workspace layout (all 16B aligned)
  const size_t OFF_QKVWT = 0;                       // 1152*384*2   = 884736
  const size_t OFF_MWT   = 884736;                  // 384*384*2    = 294912
  const size_t OFF_BIAS  = OFF_MWT + 294912;        // 12*64*64*4   = 196608
  const size_t OFF_QB    = OFF_BIAS + 196608;       // 1152*4       = 4608
  const size_t OFF_ATTN  = OFF_QB + 4608;           // 131072*384*2 = 100663296
  const size_t NEED      = OFF_ATTN + (size_t)100663296;
  if (ws_size < NEED) return;  // insufficient scratch: fail loudly (poisoned out)

  char* ws = (char*)d_ws;
  bf16_t* qkv_wT  = (bf16_t*)(ws + OFF_QKVWT);
  bf16_t* mwT     = (bf16_t*)(ws + OFF_MWT);
  float*  biasx   = (float*)(ws + OFF_BIAS);
  float*  qkvb_s  = (float*)(ws + OFF_QB);
  bf16_t* attnbuf = (bf16_t*)(ws + OFF_ATTN);

  prep_kernel<<<2501, 256, 0, stream>>>(qkv_w, qkv_b, merge_w, bias_table,
                                        rel_index, qkv_wT, mwT, biasx, qkvb_s);

  hipFuncSetAttribute(reinterpret_cast<const void*>(fused_qkv_attn),
                      hipFuncAttributeMaxDynamicSharedMemorySize, LDS_BYTES);
  fused_qkv_attn<<<NBLK, 512, LDS_BYTES, stream>>>(x, qkv_wT, qkvb_s, biasx, attnbuf);

  merge_gemm<<<NBLK, 512, 0, stream>>>(attnbuf, mwT, merge_b, out);
}